// Round 12
// baseline (148.688 us; speedup 1.0000x reference)
//
#include <hip/hip_runtime.h>

// MHA forward: H=16, N=2048, d_model=1024, d_k=64.
// d_out = [ out (2048x1024 f32) | p_attn (16x2048x2048 f32) ]
// Pipeline: cvt(f32->bf16 + mask bias) -> QKV proj (gload_lds GEMM, V stored
// transposed) -> fused attn8 (32x32x16 MFMA core: 4 waves = 2 row-groups x
// 2 j-groups, KVBLK=64 dbuf, counted vmcnt keeps stores+mbias in flight,
// p written once via LDS-readback NT f32 stores) -> out proj.

#define NTOK 2048
#define DMODEL 1024
#define NHEAD 16
#define DKH 64

typedef __attribute__((ext_vector_type(8))) short bf16x8;
typedef __attribute__((ext_vector_type(4))) float f32x4;
typedef __attribute__((ext_vector_type(16))) float f32x16;

#define WAITVMC(n)                                          \
  do {                                                      \
    asm volatile("s_waitcnt vmcnt(" n ")" ::: "memory");    \
    __builtin_amdgcn_sched_barrier(0);                      \
  } while (0)
#define BARRIER()                                           \
  do {                                                      \
    __builtin_amdgcn_s_barrier();                           \
    __builtin_amdgcn_sched_barrier(0);                      \
  } while (0)

__device__ __forceinline__ unsigned short f2bf(float x) {
  unsigned int u = __builtin_bit_cast(unsigned int, x);
  u += 0x7fffu + ((u >> 16) & 1u);   // RNE
  return (unsigned short)(u >> 16);
}
__device__ __forceinline__ unsigned int pkbf(float a, float b) {
  return (unsigned int)f2bf(a) | ((unsigned int)f2bf(b) << 16);
}

__device__ __forceinline__ void gl16(const void* g, void* l) {
  __builtin_amdgcn_global_load_lds((const __attribute__((address_space(1))) void*)g,
                                   (__attribute__((address_space(3))) void*)l, 16, 0, 0);
}

// Async-stage ROWS x 64 bf16 (128B rows) into LDS; NW waves share the job.
// Linear LDS dest + source-side XOR swizzle (read side XORs (row&7)<<4).
template<int ROWS, int NW>
__device__ __forceinline__ void stage_async(const unsigned short* src, int ld,
                                            char* lds, int w, int lane) {
  constexpr int RPW = ROWS / NW;
#pragma unroll
  for (int i = 0; i < RPW / 8; ++i) {
    const int row = w * RPW + i * 8 + (lane >> 3);
    const unsigned short* g = src + (size_t)row * ld + (((lane & 7) ^ (row & 7)) * 8);
    gl16(g, lds + (size_t)(w * RPW + i * 8) * 128);
  }
}

__device__ __forceinline__ bf16x8 ldsfrag(const char* lds, int r, int kb) {
  return *(const bf16x8*)(lds + r * 128 + (kb ^ ((r & 7) << 4)));
}

// ---------------- convert f32 -> bf16 (7 arrays) + mask bias (z==7) --------
struct CvtP {
  const float* src[7];
  unsigned short* dst[7];
  int n8[8];
  const int* mask;
  float* mbias;
};
__global__ __launch_bounds__(256) void cvt_all(CvtP P) {
  const int a = blockIdx.z;
  const int i = blockIdx.x * 256 + threadIdx.x;
  if (i >= P.n8[a]) return;
  if (a == 7) {
#pragma unroll
    for (int r = 0; r < 8; ++r) {
      int j = i * 8 + r;
      P.mbias[j] = P.mask[j] ? 0.0f : -1e30f;
    }
    return;
  }
  const float4* s = (const float4*)P.src[a];
  float4 v0 = s[i * 2], v1 = s[i * 2 + 1];
  ushort4 h0, h1;
  h0.x = f2bf(v0.x); h0.y = f2bf(v0.y); h0.z = f2bf(v0.z); h0.w = f2bf(v0.w);
  h1.x = f2bf(v1.x); h1.y = f2bf(v1.y); h1.z = f2bf(v1.z); h1.w = f2bf(v1.w);
  ((ushort4*)P.dst[a])[i * 2] = h0;
  ((ushort4*)P.dst[a])[i * 2 + 1] = h1;
}

// ---------------- GEMM: C[m,n] = sum_k A[m,k]B[n,k] + bias[n] ---------------
struct GemmP2 {
  const unsigned short* A[3];
  const unsigned short* B[3];
  const float* bias[3];
  unsigned short* Cb16;
  float* Cf32;
  unsigned short* VTd;
  long long sC;
  int lda, ldb, ldc, Nn, K;
};

template<int BM, bool OUTF32, bool VTRANS>
__global__ __launch_bounds__(256) void gemm_glds(GemmP2 P) {
  constexpr int BN = 128, WN = 64, FN = 4;
  constexpr int WM = BM / 2, FM = WM / 16;
  __shared__ char ldsA[BM * 128];
  __shared__ char ldsB[BN * 128];
  const int tid = threadIdx.x;
  const int lane = tid & 63, w = tid >> 6;
  const int l15 = lane & 15, lhi = lane >> 4;
  const int z = blockIdx.z;
  const int zi = (gridDim.z == 3) ? z : 0;
  const int ntn = P.Nn / BN;
  const int m0 = ((int)blockIdx.x / ntn) * BM;
  const int n0 = ((int)blockIdx.x % ntn) * BN;
  const unsigned short* Ab = P.A[zi] + (size_t)m0 * P.lda;
  const unsigned short* Bb = P.B[zi] + (size_t)n0 * P.ldb;
  const int wm = w >> 1, wn = w & 1;

  f32x4 acc[FM][FN] = {};
  for (int k0 = 0; k0 < P.K; k0 += 64) {
    stage_async<BM, 4>(Ab + k0, P.lda, ldsA, w, lane);
    stage_async<BN, 4>(Bb + k0, P.ldb, ldsB, w, lane);
    __syncthreads();
#pragma unroll
    for (int kk = 0; kk < 2; ++kk) {
      const int kb = kk * 64 + lhi * 16;
      bf16x8 a[FM], b[FN];
#pragma unroll
      for (int i = 0; i < FM; ++i) a[i] = ldsfrag(ldsA, wm * WM + i * 16 + l15, kb);
#pragma unroll
      for (int j = 0; j < FN; ++j) b[j] = ldsfrag(ldsB, wn * WN + j * 16 + l15, kb);
#pragma unroll
      for (int i = 0; i < FM; ++i)
#pragma unroll
        for (int j = 0; j < FN; ++j)
          acc[i][j] = __builtin_amdgcn_mfma_f32_16x16x32_bf16(a[i], b[j], acc[i][j], 0, 0, 0);
    }
    __syncthreads();
  }

  const int rbase = m0 + wm * WM + lhi * 4;
  const int cbase = n0 + wn * WN + l15;
  if (VTRANS && z == 2) {
#pragma unroll
    for (int j = 0; j < FN; ++j) {
      const int col = cbase + j * 16;
      const float badd = P.bias[zi][col];
#pragma unroll
      for (int i = 0; i < FM; ++i) {
        ushort4 t;
        t.x = f2bf(acc[i][j][0] + badd); t.y = f2bf(acc[i][j][1] + badd);
        t.z = f2bf(acc[i][j][2] + badd); t.w = f2bf(acc[i][j][3] + badd);
        *(ushort4*)(P.VTd + (size_t)col * NTOK + rbase + i * 16) = t;
      }
    }
    return;
  }
#pragma unroll
  for (int j = 0; j < FN; ++j) {
    const int col = cbase + j * 16;
    const float badd = P.bias[zi] ? P.bias[zi][col] : 0.0f;
#pragma unroll
    for (int i = 0; i < FM; ++i) {
#pragma unroll
      for (int rg = 0; rg < 4; ++rg) {
        const int row = rbase + i * 16 + rg;
        const float v = acc[i][j][rg] + badd;
        if constexpr (OUTF32)
          P.Cf32[(size_t)row * P.ldc + col] = v;
        else
          P.Cb16[(size_t)z * P.sC + (size_t)row * P.ldc + col] = f2bf(v);
      }
    }
  }
}

// ---------------- fused attention v8: 32x32x16 MFMA core --------------------
// Grid 512: h = 2*(id&7)+((id>>3)&1), q0 = (id>>4)*64 (XCD head-pair groups).
// 256 thr = 4 waves: rg = w>>1 owns q-rows rg*32..+32; jg = w&1 owns j half.
// Swapped QK^T via mfma_32x32x16: sacc col=lane&31 -> q-row rg*32+(lane&31);
// j per reg = jb*32 + (reg&3)+8*(reg>>2)+4*(lane>>5). Row sums lane-local + 1
// shfl_xor(32). KVBLK=64 dbuf (gload_lds); LDS = 80KB -> 2 blocks/CU.
// Counted vmcnt: pass-B top waits vmcnt(16) = retire 8 gl16 only; 8 mbias
// loads + 8 NT p-stores ride across iterations. p via bf16 P-tile readback ->
// NT f32x4, 128B contiguous per row per instruction.
__global__ __launch_bounds__(256, 2) void attn8(const unsigned short* __restrict__ QP,
                                                const unsigned short* __restrict__ KP,
                                                const unsigned short* __restrict__ VT,
                                                const float* __restrict__ mbias,
                                                float* __restrict__ p,
                                                unsigned short* __restrict__ XB) {
  __shared__ char LDS[81920];
  const int tid = threadIdx.x;
  const int lane = tid & 63, w = tid >> 6;
  const int rg = w >> 1, jg = w & 1;
  const int m31 = lane & 31, hi = lane >> 5;
  const int id = blockIdx.x;
  const int h = 2 * (id & 7) + ((id >> 3) & 1);
  const int q0 = (id >> 4) * 64;
  const int row_q = rg * 32 + m31;
  const int swq = (row_q & 7) << 4;
  const int swm = (m31 & 7) << 4;          // rows m31 and m31+32 share (row&7)
  constexpr float CEXP = 0.1803368801111204f;  // log2(e)/8

  char* ldsKb[2] = {LDS + jg * 16384, LDS + jg * 16384 + 8192};
  char* ldsVb[2] = {LDS + 32768 + jg * 16384, LDS + 32768 + jg * 16384 + 8192};
  char* ldsPj = LDS + 65536 + jg * 8192;   // [64 q-rows][64 j] bf16 per jg
  char* ldsQ = LDS + 65536;                // Q staging (overwritten by jg0 P)
  float* ldsR = (float*)(LDS + 65536 + 8192);  // rsum exchange (jg1 P region)

  // Q -> registers (B-operand frags: col=lane&31 -> own row_q; k=hi*8+e)
  stage_async<64, 4>(QP + (size_t)q0 * DMODEL + h * DKH, DMODEL, ldsQ, w, lane);
  __syncthreads();
  bf16x8 qf[4];
#pragma unroll
  for (int kt = 0; kt < 4; ++kt)
    qf[kt] = *(const bf16x8*)(ldsQ + row_q * 128 + ((kt * 32 + hi * 16) ^ swq));

  const unsigned short* Kh = KP + (size_t)(jg * 1024) * DMODEL + h * DKH;
  const unsigned short* Vh = VT + (size_t)h * DKH * NTOK + jg * 1024;
  const float* mbh = mbias + jg * 1024;

  // ---- pass A: partial row sums (j half) ----
  float rsum = 0.0f;
  float4 m4[8];
  stage_async<64, 2>(Kh, DMODEL, ldsKb[0], rg, lane);
#pragma unroll
  for (int q = 0; q < 8; ++q)
    m4[q] = *(const float4*)(mbh + (q >> 2) * 32 + (q & 3) * 8 + hi * 4);
  int b = 0;
  for (int it = 0; it < 16; ++it) {
    WAITVMC("8");          // retire the 4 gl16; mbias may ride
    BARRIER();
    if (it < 15)
      stage_async<64, 2>(Kh + (size_t)(it + 1) * 64 * DMODEL, DMODEL, ldsKb[b ^ 1], rg, lane);
    __builtin_amdgcn_sched_barrier(0);
    f32x16 s0 = {}, s1 = {};
#pragma unroll
    for (int kt = 0; kt < 4; ++kt) {
      bf16x8 k0 = *(const bf16x8*)(ldsKb[b] + m31 * 128 + ((kt * 32 + hi * 16) ^ swm));
      bf16x8 k1 = *(const bf16x8*)(ldsKb[b] + (32 + m31) * 128 + ((kt * 32 + hi * 16) ^ swm));
      s0 = __builtin_amdgcn_mfma_f32_32x32x16_bf16(k0, qf[kt], s0, 0, 0, 0);
      s1 = __builtin_amdgcn_mfma_f32_32x32x16_bf16(k1, qf[kt], s1, 0, 0, 0);
    }
#pragma unroll
    for (int rq = 0; rq < 4; ++rq) {
      rsum += exp2f(s0[rq * 4 + 0] * CEXP + m4[rq].x) + exp2f(s0[rq * 4 + 1] * CEXP + m4[rq].y) +
              exp2f(s0[rq * 4 + 2] * CEXP + m4[rq].z) + exp2f(s0[rq * 4 + 3] * CEXP + m4[rq].w);
      rsum += exp2f(s1[rq * 4 + 0] * CEXP + m4[4 + rq].x) + exp2f(s1[rq * 4 + 1] * CEXP + m4[4 + rq].y) +
              exp2f(s1[rq * 4 + 2] * CEXP + m4[4 + rq].z) + exp2f(s1[rq * 4 + 3] * CEXP + m4[4 + rq].w);
    }
    if (it < 15) {
      const float* mb2 = mbh + (it + 1) * 64;
#pragma unroll
      for (int q = 0; q < 8; ++q)
        m4[q] = *(const float4*)(mb2 + (q >> 2) * 32 + (q & 3) * 8 + hi * 4);
    }
    b ^= 1;
  }
  rsum += __shfl_xor(rsum, 32, 64);
  if (lane < 32) ldsR[jg * 64 + row_q] = rsum;
  BARRIER();
  const float lr = -log2f(ldsR[row_q] + ldsR[64 + row_q]);

  // ---- pass B: QK^T again; e -> bf16 P tile; PV; p via readback NT f32 ----
  f32x16 x0 = {}, x1 = {};
  stage_async<64, 2>(Kh, DMODEL, ldsKb[0], rg, lane);
  stage_async<64, 2>(Vh, NTOK, ldsVb[0], rg, lane);
#pragma unroll
  for (int q = 0; q < 8; ++q)
    m4[q] = *(const float4*)(mbh + (q >> 2) * 32 + (q & 3) * 8 + hi * 4);
  b = 0;
  for (int it = 0; it < 16; ++it) {
    const int j0 = it * 64;
    if (it == 0) { WAITVMC("8"); } else { WAITVMC("16"); }
    BARRIER();
    if (it < 15) {
      stage_async<64, 2>(Kh + (size_t)(j0 + 64) * DMODEL, DMODEL, ldsKb[b ^ 1], rg, lane);
      stage_async<64, 2>(Vh + j0 + 64, NTOK, ldsVb[b ^ 1], rg, lane);
    }
    __builtin_amdgcn_sched_barrier(0);
    f32x16 s0 = {}, s1 = {};
#pragma unroll
    for (int kt = 0; kt < 4; ++kt) {
      bf16x8 k0 = *(const bf16x8*)(ldsKb[b] + m31 * 128 + ((kt * 32 + hi * 16) ^ swm));
      bf16x8 k1 = *(const bf16x8*)(ldsKb[b] + (32 + m31) * 128 + ((kt * 32 + hi * 16) ^ swm));
      s0 = __builtin_amdgcn_mfma_f32_32x32x16_bf16(k0, qf[kt], s0, 0, 0, 0);
      s1 = __builtin_amdgcn_mfma_f32_32x32x16_bf16(k1, qf[kt], s1, 0, 0, 0);
    }
    // e = exp2(s*C + mb + lr) -> bf16 pairs -> wave-private P rows (in-order
    // LDS per wave: no barrier between these writes and the reads below)
#pragma unroll
    for (int rq = 0; rq < 4; ++rq) {
      uint2 u;
      u.x = pkbf(exp2f(s0[rq * 4 + 0] * CEXP + m4[rq].x + lr),
                 exp2f(s0[rq * 4 + 1] * CEXP + m4[rq].y + lr));
      u.y = pkbf(exp2f(s0[rq * 4 + 2] * CEXP + m4[rq].z + lr),
                 exp2f(s0[rq * 4 + 3] * CEXP + m4[rq].w + lr));
      *(uint2*)(ldsPj + row_q * 128 + ((rq * 16 + hi * 8) ^ swq)) = u;
      uint2 v;
      v.x = pkbf(exp2f(s1[rq * 4 + 0] * CEXP + m4[4 + rq].x + lr),
                 exp2f(s1[rq * 4 + 1] * CEXP + m4[4 + rq].y + lr));
      v.y = pkbf(exp2f(s1[rq * 4 + 2] * CEXP + m4[4 + rq].z + lr),
                 exp2f(s1[rq * 4 + 3] * CEXP + m4[4 + rq].w + lr));
      *(uint2*)(ldsPj + row_q * 128 + ((64 + rq * 16 + hi * 8) ^ swq)) = v;
    }
    // PV: x[d][m] accumulate; vf = A (rows d), pf = B (cols m = own row_q)
#pragma unroll
    for (int ks = 0; ks < 4; ++ks) {
      bf16x8 pf = *(const bf16x8*)(ldsPj + row_q * 128 + ((ks * 32 + hi * 16) ^ swq));
      bf16x8 v0 = *(const bf16x8*)(ldsVb[b] + m31 * 128 + ((ks * 32 + hi * 16) ^ swm));
      bf16x8 v1 = *(const bf16x8*)(ldsVb[b] + (32 + m31) * 128 + ((ks * 32 + hi * 16) ^ swm));
      x0 = __builtin_amdgcn_mfma_f32_32x32x16_bf16(v0, pf, x0, 0, 0, 0);
      x1 = __builtin_amdgcn_mfma_f32_32x32x16_bf16(v1, pf, x1, 0, 0, 0);
    }
    // mbias reload AFTER use (anti-dep keeps order; rides the vmcnt queue)
    if (it < 15) {
      const float* mb2 = mbh + (j0 + 64);
#pragma unroll
      for (int q = 0; q < 8; ++q)
        m4[q] = *(const float4*)(mb2 + (q >> 2) * 32 + (q & 3) * 8 + hi * 4);
    }
    // p-store: readback own rows -> NT f32x4; 8 insts, 128B runs per row
    float* pb = p + ((size_t)h * NTOK + q0) * NTOK + jg * 1024 + j0;
#pragma unroll
    for (int rb = 0; rb < 4; ++rb) {
      const int rr = rg * 32 + rb * 8 + (lane >> 3);
      const int swr = (rr & 7) << 4;
#pragma unroll
      for (int hh = 0; hh < 2; ++hh) {
        const uint2 u = *(const uint2*)(ldsPj + rr * 128 + ((((lane & 7) * 8) + hh * 64) ^ swr));
        f32x4 f;
        f[0] = __builtin_bit_cast(float, u.x << 16);
        f[1] = __builtin_bit_cast(float, u.x & 0xffff0000u);
        f[2] = __builtin_bit_cast(float, u.y << 16);
        f[3] = __builtin_bit_cast(float, u.y & 0xffff0000u);
        __builtin_nontemporal_store(f, (f32x4*)(pb + (size_t)rr * NTOK + hh * 32 + (lane & 7) * 4));
      }
    }
    b ^= 1;
  }

  // ---- epilogue: combine x across jg via LDS (reuse K region), store XB ----
  float* ldsX = (float*)LDS;
  BARRIER();
  if (jg == 1) {
#pragma unroll
    for (int db = 0; db < 2; ++db) {
      const f32x16 xx = db ? x1 : x0;
#pragma unroll
      for (int rq = 0; rq < 4; ++rq) {
        f32x4 v;
        v[0] = xx[rq * 4 + 0]; v[1] = xx[rq * 4 + 1];
        v[2] = xx[rq * 4 + 2]; v[3] = xx[rq * 4 + 3];
        *(f32x4*)((char*)ldsX + row_q * 256 + ((db * 128 + rq * 32 + hi * 16) ^ swq)) = v;
      }
    }
  }
  BARRIER();
  if (jg == 0) {
    unsigned short* xr = XB + (size_t)(q0 + row_q) * DMODEL + h * DKH;
#pragma unroll
    for (int db = 0; db < 2; ++db) {
      const f32x16 xx = db ? x1 : x0;
#pragma unroll
      for (int rq = 0; rq < 4; ++rq) {
        f32x4 o = *(const f32x4*)((char*)ldsX + row_q * 256 + ((db * 128 + rq * 32 + hi * 16) ^ swq));
        o[0] += xx[rq * 4 + 0]; o[1] += xx[rq * 4 + 1];
        o[2] += xx[rq * 4 + 2]; o[3] += xx[rq * 4 + 3];
        ushort4 t;
        t.x = f2bf(o[0]); t.y = f2bf(o[1]); t.z = f2bf(o[2]); t.w = f2bf(o[3]);
        *(ushort4*)(xr + db * 32 + rq * 8 + hi * 4) = t;
      }
    }
  }
}

extern "C" void kernel_launch(void* const* d_in, const int* in_sizes, int n_in,
                              void* d_out, int out_size, void* d_ws, size_t ws_size,
                              hipStream_t stream) {
  (void)in_sizes; (void)n_in; (void)out_size; (void)ws_size;
  const float* query = (const float*)d_in[0];
  const float* key_  = (const float*)d_in[1];
  const float* value = (const float*)d_in[2];
  const int*   mask  = (const int*)d_in[3];
  const float* Wq = (const float*)d_in[4];
  const float* bq = (const float*)d_in[5];
  const float* Wk = (const float*)d_in[6];
  const float* bk = (const float*)d_in[7];
  const float* Wv = (const float*)d_in[8];
  const float* bv = (const float*)d_in[9];
  const float* Wo = (const float*)d_in[10];
  const float* bo = (const float*)d_in[11];

  float* out = (float*)d_out;
  float* p = out + (size_t)NTOK * DMODEL;

  char* ws = (char*)d_ws;
  unsigned short* QP  = (unsigned short*)(ws);                 // 4MB
  unsigned short* KP  = (unsigned short*)(ws + (4u << 20));    // 4MB
  unsigned short* VT  = (unsigned short*)(ws + (8u << 20));    // 4MB (16,64,2048)
  unsigned short* XB  = (unsigned short*)(ws + (12u << 20));   // 4MB
  unsigned short* qB  = (unsigned short*)(ws + (16u << 20));   // 4MB
  unsigned short* kB  = (unsigned short*)(ws + (20u << 20));
  unsigned short* vB  = (unsigned short*)(ws + (24u << 20));
  unsigned short* WqB = (unsigned short*)(ws + (28u << 20));   // 2MB each
  unsigned short* WkB = (unsigned short*)(ws + (30u << 20));
  unsigned short* WvB = (unsigned short*)(ws + (32u << 20));
  unsigned short* WoB = (unsigned short*)(ws + (34u << 20));
  float* mbias = (float*)(ws + (36u << 20));                   // 8KB

  // 1. convert everything to bf16 + mask bias
  {
    CvtP C = {};
    C.src[0] = query; C.dst[0] = qB;  C.n8[0] = NTOK * DMODEL / 8;
    C.src[1] = key_;  C.dst[1] = kB;  C.n8[1] = NTOK * DMODEL / 8;
    C.src[2] = value; C.dst[2] = vB;  C.n8[2] = NTOK * DMODEL / 8;
    C.src[3] = Wq;    C.dst[3] = WqB; C.n8[3] = DMODEL * DMODEL / 8;
    C.src[4] = Wk;    C.dst[4] = WkB; C.n8[4] = DMODEL * DMODEL / 8;
    C.src[5] = Wv;    C.dst[5] = WvB; C.n8[5] = DMODEL * DMODEL / 8;
    C.src[6] = Wo;    C.dst[6] = WoB; C.n8[6] = DMODEL * DMODEL / 8;
    C.n8[7] = NTOK / 8;
    C.mask = mask; C.mbias = mbias;
    cvt_all<<<dim3(1024, 1, 8), 256, 0, stream>>>(C);
  }
  // 2. QKV projections (z=2 -> V stored transposed into VT)
  {
    GemmP2 P = {};
    P.A[0] = qB; P.A[1] = kB; P.A[2] = vB;
    P.B[0] = WqB; P.B[1] = WkB; P.B[2] = WvB;
    P.bias[0] = bq; P.bias[1] = bk; P.bias[2] = bv;
    P.Cb16 = QP; P.VTd = VT; P.sC = (long long)NTOK * DMODEL;
    P.lda = DMODEL; P.ldb = DMODEL; P.ldc = DMODEL; P.Nn = DMODEL; P.K = DMODEL;
    gemm_glds<128, false, true>
        <<<dim3((NTOK / 128) * (DMODEL / 128), 1, 3), 256, 0, stream>>>(P);
  }
  // 3. fused attention v8 (32x32 core)
  attn8<<<dim3(512), 256, 0, stream>>>(QP, KP, VT, mbias, p, XB);
  // 4. out projection
  {
    GemmP2 P = {};
    P.A[0] = XB; P.B[0] = WoB; P.bias[0] = bo;
    P.Cf32 = out; P.sC = 0;
    P.lda = DMODEL; P.ldb = DMODEL; P.ldc = DMODEL; P.Nn = DMODEL; P.K = DMODEL;
    gemm_glds<64, true, false>
        <<<dim3((NTOK / 64) * (DMODEL / 128), 1, 1), 256, 0, stream>>>(P);
  }
}

// Round 13
// 145.272 us; speedup vs baseline: 1.0235x; 1.0235x over previous
//
#include <hip/hip_runtime.h>

// MHA forward: H=16, N=2048, d_model=1024, d_k=64.
// d_out = [ out (2048x1024 f32) | p_attn (16x2048x2048 f32) ]
// Pipeline: cvt(f32->bf16 + mask bias) -> QKV proj (BM=64 -> grid 768, 3
// blocks/CU; V stored transposed) -> fused attn8 (32x32 core + setprio) ->
// out proj (64x64 tile -> grid 512, 2 blocks/CU).

#define NTOK 2048
#define DMODEL 1024
#define NHEAD 16
#define DKH 64

typedef __attribute__((ext_vector_type(8))) short bf16x8;
typedef __attribute__((ext_vector_type(4))) float f32x4;
typedef __attribute__((ext_vector_type(16))) float f32x16;

#define WAITVMC(n)                                          \
  do {                                                      \
    asm volatile("s_waitcnt vmcnt(" n ")" ::: "memory");    \
    __builtin_amdgcn_sched_barrier(0);                      \
  } while (0)
#define BARRIER()                                           \
  do {                                                      \
    __builtin_amdgcn_s_barrier();                           \
    __builtin_amdgcn_sched_barrier(0);                      \
  } while (0)

__device__ __forceinline__ unsigned short f2bf(float x) {
  unsigned int u = __builtin_bit_cast(unsigned int, x);
  u += 0x7fffu + ((u >> 16) & 1u);   // RNE
  return (unsigned short)(u >> 16);
}
__device__ __forceinline__ unsigned int pkbf(float a, float b) {
  return (unsigned int)f2bf(a) | ((unsigned int)f2bf(b) << 16);
}

__device__ __forceinline__ void gl16(const void* g, void* l) {
  __builtin_amdgcn_global_load_lds((const __attribute__((address_space(1))) void*)g,
                                   (__attribute__((address_space(3))) void*)l, 16, 0, 0);
}

// Async-stage ROWS x 64 bf16 (128B rows) into LDS; NW waves share the job.
// Linear LDS dest + source-side XOR swizzle (read side XORs (row&7)<<4).
template<int ROWS, int NW>
__device__ __forceinline__ void stage_async(const unsigned short* src, int ld,
                                            char* lds, int w, int lane) {
  constexpr int RPW = ROWS / NW;
#pragma unroll
  for (int i = 0; i < RPW / 8; ++i) {
    const int row = w * RPW + i * 8 + (lane >> 3);
    const unsigned short* g = src + (size_t)row * ld + (((lane & 7) ^ (row & 7)) * 8);
    gl16(g, lds + (size_t)(w * RPW + i * 8) * 128);
  }
}

__device__ __forceinline__ bf16x8 ldsfrag(const char* lds, int r, int kb) {
  return *(const bf16x8*)(lds + r * 128 + (kb ^ ((r & 7) << 4)));
}

// ---------------- convert f32 -> bf16 (7 arrays) + mask bias (z==7) --------
struct CvtP {
  const float* src[7];
  unsigned short* dst[7];
  int n8[8];
  const int* mask;
  float* mbias;
};
__global__ __launch_bounds__(256) void cvt_all(CvtP P) {
  const int a = blockIdx.z;
  const int i = blockIdx.x * 256 + threadIdx.x;
  if (i >= P.n8[a]) return;
  if (a == 7) {
#pragma unroll
    for (int r = 0; r < 8; ++r) {
      int j = i * 8 + r;
      P.mbias[j] = P.mask[j] ? 0.0f : -1e30f;
    }
    return;
  }
  const float4* s = (const float4*)P.src[a];
  float4 v0 = s[i * 2], v1 = s[i * 2 + 1];
  ushort4 h0, h1;
  h0.x = f2bf(v0.x); h0.y = f2bf(v0.y); h0.z = f2bf(v0.z); h0.w = f2bf(v0.w);
  h1.x = f2bf(v1.x); h1.y = f2bf(v1.y); h1.z = f2bf(v1.z); h1.w = f2bf(v1.w);
  ((ushort4*)P.dst[a])[i * 2] = h0;
  ((ushort4*)P.dst[a])[i * 2 + 1] = h1;
}

// ---------------- GEMM: C[m,n] = sum_k A[m,k]B[n,k] + bias[n] ---------------
struct GemmP2 {
  const unsigned short* A[3];
  const unsigned short* B[3];
  const float* bias[3];
  unsigned short* Cb16;
  float* Cf32;
  unsigned short* VTd;
  long long sC;
  int lda, ldb, ldc, Nn, K;
};

template<int BM, int BN, bool OUTF32, bool VTRANS>
__global__ __launch_bounds__(256) void gemm_glds(GemmP2 P) {
  constexpr int WN = BN / 2, FN = WN / 16;
  constexpr int WM = BM / 2, FM = WM / 16;
  __shared__ char ldsA[BM * 128];
  __shared__ char ldsB[BN * 128];
  const int tid = threadIdx.x;
  const int lane = tid & 63, w = tid >> 6;
  const int l15 = lane & 15, lhi = lane >> 4;
  const int z = blockIdx.z;
  const int zi = (gridDim.z == 3) ? z : 0;
  const int ntn = P.Nn / BN;
  const int m0 = ((int)blockIdx.x / ntn) * BM;
  const int n0 = ((int)blockIdx.x % ntn) * BN;
  const unsigned short* Ab = P.A[zi] + (size_t)m0 * P.lda;
  const unsigned short* Bb = P.B[zi] + (size_t)n0 * P.ldb;
  const int wm = w >> 1, wn = w & 1;

  f32x4 acc[FM][FN] = {};
  for (int k0 = 0; k0 < P.K; k0 += 64) {
    stage_async<BM, 4>(Ab + k0, P.lda, ldsA, w, lane);
    stage_async<BN, 4>(Bb + k0, P.ldb, ldsB, w, lane);
    __syncthreads();
#pragma unroll
    for (int kk = 0; kk < 2; ++kk) {
      const int kb = kk * 64 + lhi * 16;
      bf16x8 a[FM], b[FN];
#pragma unroll
      for (int i = 0; i < FM; ++i) a[i] = ldsfrag(ldsA, wm * WM + i * 16 + l15, kb);
#pragma unroll
      for (int j = 0; j < FN; ++j) b[j] = ldsfrag(ldsB, wn * WN + j * 16 + l15, kb);
#pragma unroll
      for (int i = 0; i < FM; ++i)
#pragma unroll
        for (int j = 0; j < FN; ++j)
          acc[i][j] = __builtin_amdgcn_mfma_f32_16x16x32_bf16(a[i], b[j], acc[i][j], 0, 0, 0);
    }
    __syncthreads();
  }

  const int rbase = m0 + wm * WM + lhi * 4;
  const int cbase = n0 + wn * WN + l15;
  if (VTRANS && z == 2) {
#pragma unroll
    for (int j = 0; j < FN; ++j) {
      const int col = cbase + j * 16;
      const float badd = P.bias[zi][col];
#pragma unroll
      for (int i = 0; i < FM; ++i) {
        ushort4 t;
        t.x = f2bf(acc[i][j][0] + badd); t.y = f2bf(acc[i][j][1] + badd);
        t.z = f2bf(acc[i][j][2] + badd); t.w = f2bf(acc[i][j][3] + badd);
        *(ushort4*)(P.VTd + (size_t)col * NTOK + rbase + i * 16) = t;
      }
    }
    return;
  }
#pragma unroll
  for (int j = 0; j < FN; ++j) {
    const int col = cbase + j * 16;
    const float badd = P.bias[zi] ? P.bias[zi][col] : 0.0f;
#pragma unroll
    for (int i = 0; i < FM; ++i) {
#pragma unroll
      for (int rg = 0; rg < 4; ++rg) {
        const int row = rbase + i * 16 + rg;
        const float v = acc[i][j][rg] + badd;
        if constexpr (OUTF32)
          P.Cf32[(size_t)row * P.ldc + col] = v;
        else
          P.Cb16[(size_t)z * P.sC + (size_t)row * P.ldc + col] = f2bf(v);
      }
    }
  }
}

// ---------------- fused attention v8: 32x32x16 MFMA core --------------------
// (structure identical to R12's passing kernel; + s_setprio around MFMA)
__global__ __launch_bounds__(256, 2) void attn8(const unsigned short* __restrict__ QP,
                                                const unsigned short* __restrict__ KP,
                                                const unsigned short* __restrict__ VT,
                                                const float* __restrict__ mbias,
                                                float* __restrict__ p,
                                                unsigned short* __restrict__ XB) {
  __shared__ char LDS[81920];
  const int tid = threadIdx.x;
  const int lane = tid & 63, w = tid >> 6;
  const int rg = w >> 1, jg = w & 1;
  const int m31 = lane & 31, hi = lane >> 5;
  const int id = blockIdx.x;
  const int h = 2 * (id & 7) + ((id >> 3) & 1);
  const int q0 = (id >> 4) * 64;
  const int row_q = rg * 32 + m31;
  const int swq = (row_q & 7) << 4;
  const int swm = (m31 & 7) << 4;
  constexpr float CEXP = 0.1803368801111204f;  // log2(e)/8

  char* ldsKb[2] = {LDS + jg * 16384, LDS + jg * 16384 + 8192};
  char* ldsVb[2] = {LDS + 32768 + jg * 16384, LDS + 32768 + jg * 16384 + 8192};
  char* ldsPj = LDS + 65536 + jg * 8192;
  char* ldsQ = LDS + 65536;
  float* ldsR = (float*)(LDS + 65536 + 8192);

  stage_async<64, 4>(QP + (size_t)q0 * DMODEL + h * DKH, DMODEL, ldsQ, w, lane);
  __syncthreads();
  bf16x8 qf[4];
#pragma unroll
  for (int kt = 0; kt < 4; ++kt)
    qf[kt] = *(const bf16x8*)(ldsQ + row_q * 128 + ((kt * 32 + hi * 16) ^ swq));

  const unsigned short* Kh = KP + (size_t)(jg * 1024) * DMODEL + h * DKH;
  const unsigned short* Vh = VT + (size_t)h * DKH * NTOK + jg * 1024;
  const float* mbh = mbias + jg * 1024;

  // ---- pass A: partial row sums (j half) ----
  float rsum = 0.0f;
  float4 m4[8];
  stage_async<64, 2>(Kh, DMODEL, ldsKb[0], rg, lane);
#pragma unroll
  for (int q = 0; q < 8; ++q)
    m4[q] = *(const float4*)(mbh + (q >> 2) * 32 + (q & 3) * 8 + hi * 4);
  int b = 0;
  for (int it = 0; it < 16; ++it) {
    WAITVMC("8");
    BARRIER();
    if (it < 15)
      stage_async<64, 2>(Kh + (size_t)(it + 1) * 64 * DMODEL, DMODEL, ldsKb[b ^ 1], rg, lane);
    __builtin_amdgcn_sched_barrier(0);
    f32x16 s0 = {}, s1 = {};
    __builtin_amdgcn_s_setprio(1);
#pragma unroll
    for (int kt = 0; kt < 4; ++kt) {
      bf16x8 k0 = *(const bf16x8*)(ldsKb[b] + m31 * 128 + ((kt * 32 + hi * 16) ^ swm));
      bf16x8 k1 = *(const bf16x8*)(ldsKb[b] + (32 + m31) * 128 + ((kt * 32 + hi * 16) ^ swm));
      s0 = __builtin_amdgcn_mfma_f32_32x32x16_bf16(k0, qf[kt], s0, 0, 0, 0);
      s1 = __builtin_amdgcn_mfma_f32_32x32x16_bf16(k1, qf[kt], s1, 0, 0, 0);
    }
    __builtin_amdgcn_s_setprio(0);
#pragma unroll
    for (int rq = 0; rq < 4; ++rq) {
      rsum += exp2f(s0[rq * 4 + 0] * CEXP + m4[rq].x) + exp2f(s0[rq * 4 + 1] * CEXP + m4[rq].y) +
              exp2f(s0[rq * 4 + 2] * CEXP + m4[rq].z) + exp2f(s0[rq * 4 + 3] * CEXP + m4[rq].w);
      rsum += exp2f(s1[rq * 4 + 0] * CEXP + m4[4 + rq].x) + exp2f(s1[rq * 4 + 1] * CEXP + m4[4 + rq].y) +
              exp2f(s1[rq * 4 + 2] * CEXP + m4[4 + rq].z) + exp2f(s1[rq * 4 + 3] * CEXP + m4[4 + rq].w);
    }
    if (it < 15) {
      const float* mb2 = mbh + (it + 1) * 64;
#pragma unroll
      for (int q = 0; q < 8; ++q)
        m4[q] = *(const float4*)(mb2 + (q >> 2) * 32 + (q & 3) * 8 + hi * 4);
    }
    b ^= 1;
  }
  rsum += __shfl_xor(rsum, 32, 64);
  if (lane < 32) ldsR[jg * 64 + row_q] = rsum;
  BARRIER();
  const float lr = -log2f(ldsR[row_q] + ldsR[64 + row_q]);

  // ---- pass B ----
  f32x16 x0 = {}, x1 = {};
  stage_async<64, 2>(Kh, DMODEL, ldsKb[0], rg, lane);
  stage_async<64, 2>(Vh, NTOK, ldsVb[0], rg, lane);
#pragma unroll
  for (int q = 0; q < 8; ++q)
    m4[q] = *(const float4*)(mbh + (q >> 2) * 32 + (q & 3) * 8 + hi * 4);
  b = 0;
  for (int it = 0; it < 16; ++it) {
    const int j0 = it * 64;
    if (it == 0) { WAITVMC("8"); } else { WAITVMC("16"); }
    BARRIER();
    if (it < 15) {
      stage_async<64, 2>(Kh + (size_t)(j0 + 64) * DMODEL, DMODEL, ldsKb[b ^ 1], rg, lane);
      stage_async<64, 2>(Vh + j0 + 64, NTOK, ldsVb[b ^ 1], rg, lane);
    }
    __builtin_amdgcn_sched_barrier(0);
    f32x16 s0 = {}, s1 = {};
    __builtin_amdgcn_s_setprio(1);
#pragma unroll
    for (int kt = 0; kt < 4; ++kt) {
      bf16x8 k0 = *(const bf16x8*)(ldsKb[b] + m31 * 128 + ((kt * 32 + hi * 16) ^ swm));
      bf16x8 k1 = *(const bf16x8*)(ldsKb[b] + (32 + m31) * 128 + ((kt * 32 + hi * 16) ^ swm));
      s0 = __builtin_amdgcn_mfma_f32_32x32x16_bf16(k0, qf[kt], s0, 0, 0, 0);
      s1 = __builtin_amdgcn_mfma_f32_32x32x16_bf16(k1, qf[kt], s1, 0, 0, 0);
    }
    __builtin_amdgcn_s_setprio(0);
#pragma unroll
    for (int rq = 0; rq < 4; ++rq) {
      uint2 u;
      u.x = pkbf(exp2f(s0[rq * 4 + 0] * CEXP + m4[rq].x + lr),
                 exp2f(s0[rq * 4 + 1] * CEXP + m4[rq].y + lr));
      u.y = pkbf(exp2f(s0[rq * 4 + 2] * CEXP + m4[rq].z + lr),
                 exp2f(s0[rq * 4 + 3] * CEXP + m4[rq].w + lr));
      *(uint2*)(ldsPj + row_q * 128 + ((rq * 16 + hi * 8) ^ swq)) = u;
      uint2 v;
      v.x = pkbf(exp2f(s1[rq * 4 + 0] * CEXP + m4[4 + rq].x + lr),
                 exp2f(s1[rq * 4 + 1] * CEXP + m4[4 + rq].y + lr));
      v.y = pkbf(exp2f(s1[rq * 4 + 2] * CEXP + m4[4 + rq].z + lr),
                 exp2f(s1[rq * 4 + 3] * CEXP + m4[4 + rq].w + lr));
      *(uint2*)(ldsPj + row_q * 128 + ((64 + rq * 16 + hi * 8) ^ swq)) = v;
    }
    __builtin_amdgcn_s_setprio(1);
#pragma unroll
    for (int ks = 0; ks < 4; ++ks) {
      bf16x8 pf = *(const bf16x8*)(ldsPj + row_q * 128 + ((ks * 32 + hi * 16) ^ swq));
      bf16x8 v0 = *(const bf16x8*)(ldsVb[b] + m31 * 128 + ((ks * 32 + hi * 16) ^ swm));
      bf16x8 v1 = *(const bf16x8*)(ldsVb[b] + (32 + m31) * 128 + ((ks * 32 + hi * 16) ^ swm));
      x0 = __builtin_amdgcn_mfma_f32_32x32x16_bf16(v0, pf, x0, 0, 0, 0);
      x1 = __builtin_amdgcn_mfma_f32_32x32x16_bf16(v1, pf, x1, 0, 0, 0);
    }
    __builtin_amdgcn_s_setprio(0);
    if (it < 15) {
      const float* mb2 = mbh + (j0 + 64);
#pragma unroll
      for (int q = 0; q < 8; ++q)
        m4[q] = *(const float4*)(mb2 + (q >> 2) * 32 + (q & 3) * 8 + hi * 4);
    }
    float* pb = p + ((size_t)h * NTOK + q0) * NTOK + jg * 1024 + j0;
#pragma unroll
    for (int rb = 0; rb < 4; ++rb) {
      const int rr = rg * 32 + rb * 8 + (lane >> 3);
      const int swr = (rr & 7) << 4;
#pragma unroll
      for (int hh = 0; hh < 2; ++hh) {
        const uint2 u = *(const uint2*)(ldsPj + rr * 128 + ((((lane & 7) * 8) + hh * 64) ^ swr));
        f32x4 f;
        f[0] = __builtin_bit_cast(float, u.x << 16);
        f[1] = __builtin_bit_cast(float, u.x & 0xffff0000u);
        f[2] = __builtin_bit_cast(float, u.y << 16);
        f[3] = __builtin_bit_cast(float, u.y & 0xffff0000u);
        __builtin_nontemporal_store(f, (f32x4*)(pb + (size_t)rr * NTOK + hh * 32 + (lane & 7) * 4));
      }
    }
    b ^= 1;
  }

  // ---- epilogue: combine x across jg via LDS, store XB ----
  float* ldsX = (float*)LDS;
  BARRIER();
  if (jg == 1) {
#pragma unroll
    for (int db = 0; db < 2; ++db) {
      const f32x16 xx = db ? x1 : x0;
#pragma unroll
      for (int rq = 0; rq < 4; ++rq) {
        f32x4 v;
        v[0] = xx[rq * 4 + 0]; v[1] = xx[rq * 4 + 1];
        v[2] = xx[rq * 4 + 2]; v[3] = xx[rq * 4 + 3];
        *(f32x4*)((char*)ldsX + row_q * 256 + ((db * 128 + rq * 32 + hi * 16) ^ swq)) = v;
      }
    }
  }
  BARRIER();
  if (jg == 0) {
    unsigned short* xr = XB + (size_t)(q0 + row_q) * DMODEL + h * DKH;
#pragma unroll
    for (int db = 0; db < 2; ++db) {
      const f32x16 xx = db ? x1 : x0;
#pragma unroll
      for (int rq = 0; rq < 4; ++rq) {
        f32x4 o = *(const f32x4*)((char*)ldsX + row_q * 256 + ((db * 128 + rq * 32 + hi * 16) ^ swq));
        o[0] += xx[rq * 4 + 0]; o[1] += xx[rq * 4 + 1];
        o[2] += xx[rq * 4 + 2]; o[3] += xx[rq * 4 + 3];
        ushort4 t;
        t.x = f2bf(o[0]); t.y = f2bf(o[1]); t.z = f2bf(o[2]); t.w = f2bf(o[3]);
        *(ushort4*)(xr + db * 32 + rq * 8 + hi * 4) = t;
      }
    }
  }
}

extern "C" void kernel_launch(void* const* d_in, const int* in_sizes, int n_in,
                              void* d_out, int out_size, void* d_ws, size_t ws_size,
                              hipStream_t stream) {
  (void)in_sizes; (void)n_in; (void)out_size; (void)ws_size;
  const float* query = (const float*)d_in[0];
  const float* key_  = (const float*)d_in[1];
  const float* value = (const float*)d_in[2];
  const int*   mask  = (const int*)d_in[3];
  const float* Wq = (const float*)d_in[4];
  const float* bq = (const float*)d_in[5];
  const float* Wk = (const float*)d_in[6];
  const float* bk = (const float*)d_in[7];
  const float* Wv = (const float*)d_in[8];
  const float* bv = (const float*)d_in[9];
  const float* Wo = (const float*)d_in[10];
  const float* bo = (const float*)d_in[11];

  float* out = (float*)d_out;
  float* p = out + (size_t)NTOK * DMODEL;

  char* ws = (char*)d_ws;
  unsigned short* QP  = (unsigned short*)(ws);                 // 4MB
  unsigned short* KP  = (unsigned short*)(ws + (4u << 20));    // 4MB
  unsigned short* VT  = (unsigned short*)(ws + (8u << 20));    // 4MB (16,64,2048)
  unsigned short* XB  = (unsigned short*)(ws + (12u << 20));   // 4MB
  unsigned short* qB  = (unsigned short*)(ws + (16u << 20));   // 4MB
  unsigned short* kB  = (unsigned short*)(ws + (20u << 20));
  unsigned short* vB  = (unsigned short*)(ws + (24u << 20));
  unsigned short* WqB = (unsigned short*)(ws + (28u << 20));   // 2MB each
  unsigned short* WkB = (unsigned short*)(ws + (30u << 20));
  unsigned short* WvB = (unsigned short*)(ws + (32u << 20));
  unsigned short* WoB = (unsigned short*)(ws + (34u << 20));
  float* mbias = (float*)(ws + (36u << 20));                   // 8KB

  // 1. convert everything to bf16 + mask bias
  {
    CvtP C = {};
    C.src[0] = query; C.dst[0] = qB;  C.n8[0] = NTOK * DMODEL / 8;
    C.src[1] = key_;  C.dst[1] = kB;  C.n8[1] = NTOK * DMODEL / 8;
    C.src[2] = value; C.dst[2] = vB;  C.n8[2] = NTOK * DMODEL / 8;
    C.src[3] = Wq;    C.dst[3] = WqB; C.n8[3] = DMODEL * DMODEL / 8;
    C.src[4] = Wk;    C.dst[4] = WkB; C.n8[4] = DMODEL * DMODEL / 8;
    C.src[5] = Wv;    C.dst[5] = WvB; C.n8[5] = DMODEL * DMODEL / 8;
    C.src[6] = Wo;    C.dst[6] = WoB; C.n8[6] = DMODEL * DMODEL / 8;
    C.n8[7] = NTOK / 8;
    C.mask = mask; C.mbias = mbias;
    cvt_all<<<dim3(1024, 1, 8), 256, 0, stream>>>(C);
  }
  // 2. QKV projections, BM=64 -> grid 768 (3 blocks/CU); z=2 stores VT
  {
    GemmP2 P = {};
    P.A[0] = qB; P.A[1] = kB; P.A[2] = vB;
    P.B[0] = WqB; P.B[1] = WkB; P.B[2] = WvB;
    P.bias[0] = bq; P.bias[1] = bk; P.bias[2] = bv;
    P.Cb16 = QP; P.VTd = VT; P.sC = (long long)NTOK * DMODEL;
    P.lda = DMODEL; P.ldb = DMODEL; P.ldc = DMODEL; P.Nn = DMODEL; P.K = DMODEL;
    gemm_glds<64, 128, false, true>
        <<<dim3((NTOK / 64) * (DMODEL / 128), 1, 3), 256, 0, stream>>>(P);
  }
  // 3. fused attention v8 (32x32 core + setprio)
  attn8<<<dim3(512), 256, 0, stream>>>(QP, KP, VT, mbias, p, XB);
  // 4. out projection, 64x64 tile -> grid 512 (2 blocks/CU)
  {
    GemmP2 P = {};
    P.A[0] = XB; P.B[0] = WoB; P.bias[0] = bo;
    P.Cf32 = out; P.sC = 0;
    P.lda = DMODEL; P.ldb = DMODEL; P.ldc = DMODEL; P.Nn = DMODEL; P.K = DMODEL;
    gemm_glds<64, 64, true, false>
        <<<dim3((NTOK / 64) * (DMODEL / 64), 1, 1), 256, 0, stream>>>(P);
  }
}